// Round 5
// baseline (154.154 us; speedup 1.0000x reference)
//
#include <hip/hip_runtime.h>

// DifferentiableProjectionLayer: 262144 independent rows of 64 assets,
// 20 iters of {box clip + simplex shift + 8 disjoint group projections}.
//
// Mapping: TWO LANES PER ROW. Lane h of a pair owns the 32 assets with
// (j>>3)&1==h — i.e. 4 assets of each of the 8 groups. Per-thread state is
// w[32]+gs[8]+u[8] ~= 58 VGPRs, fitting the compiler's preferred 64-VGPR /
// 8-waves-per-EU operating point with NO spills (R3/R4 lesson: w[64] per
// lane made the allocator shuffle through AGPRs/scratch).
// Cross-lane traffic: 8 DPP quad_perm xor-1 adds per iteration (group sums);
// the row sum is a lane-local tree over the exchanged group sums.
//
// proj_fast handles the structural case (one-hot A, uniform box bounds,
// verified wave-uniformly on device); proj_generic is the faithful general
// Dykstra fallback and early-exits when the fast kernel handled it.

#define NA 64
#define NG 8

__device__ __forceinline__ float dpp_xor1_add(float v) {
    // v += value from lane^1 (quad_perm [1,0,3,2])
    const int o = __builtin_amdgcn_update_dpp(0, __builtin_bit_cast(int, v),
                                              0xB1, 0xF, 0xF, true);
    return v + __builtin_bit_cast(float, o);
}

__device__ __forceinline__ bool structural_ok(const float* __restrict__ box_lb,
                                              const float* __restrict__ box_ub,
                                              const float* __restrict__ group_A,
                                              int l) {
    const float lb0 = box_lb[0], ub0 = box_ub[0];
    bool ok = (box_lb[l] == lb0) && (box_ub[l] == ub0) && (lb0 <= ub0);
#pragma unroll
    for (int g = 0; g < NG; ++g) {
        const float expect = ((l & 7) == g) ? 1.0f : 0.0f;
        ok = ok && (group_A[g * NA + l] == expect);
    }
    return __all(ok);
}

__global__ __launch_bounds__(256) void proj_fast(
    const float* __restrict__ x,
    const float* __restrict__ box_lb,
    const float* __restrict__ box_ub,
    const float* __restrict__ group_A,
    const float* __restrict__ group_lb,
    const float* __restrict__ group_ub,
    const int*  __restrict__ num_iter,
    float* __restrict__ out,
    int nrows)
{
    if (!structural_ok(box_lb, box_ub, group_A, threadIdx.x & 63)) return;

    const int t = blockIdx.x * blockDim.x + threadIdx.x;
    const int r = t >> 1;        // row
    const int h = t & 1;         // half: owns assets with (j>>3)&1 == h
    if (r >= nrows) return;

    const float* __restrict__ xr = x + (size_t)r * NA;
    float* __restrict__ outr = out + (size_t)r * NA;

    // local index i = 8m+g  <->  asset j = 16m + 8h + g   (m in [0,4))
    float w[32];
#pragma unroll
    for (int m = 0; m < 4; ++m)
#pragma unroll
        for (int q = 0; q < 2; ++q) {
            const float4 v = reinterpret_cast<const float4*>(xr)[4 * m + 2 * h + q];
            w[8 * m + 4 * q + 0] = v.x; w[8 * m + 4 * q + 1] = v.y;
            w[8 * m + 4 * q + 2] = v.z; w[8 * m + 4 * q + 3] = v.w;
        }

    const float lb0 = box_lb[0], ub0 = box_ub[0];    // uniform -> SGPR
    float glb_s[NG], gub_s[NG];                      // uniform -> SGPR
#pragma unroll
    for (int g = 0; g < NG; ++g) { glb_s[g] = group_lb[g]; gub_s[g] = group_ub[g]; }

    const int iters = *num_iter;

    // ns = 8 (+1e-9 vanishes in f32) => inv = 0.125 exact; analytic second
    // dot: Aw2 = Aw - e1*(8*inv) = Aw - e1.
    const float inv8 = 1.0f / (8.0f + 1e-9f);        // == 0.125f

    for (int it = 0; it < iters; ++it) {
        // box clip
#pragma unroll
        for (int i = 0; i < 32; ++i)
            w[i] = __builtin_amdgcn_fmed3f(w[i], lb0, ub0);

        // group sums: lane-local 4-term tree, then pair exchange (DPP xor1)
        float gs[NG];
#pragma unroll
        for (int g = 0; g < NG; ++g)
            gs[g] = (w[g] + w[g + 8]) + (w[g + 16] + w[g + 24]);
#pragma unroll
        for (int g = 0; g < NG; ++g)
            gs[g] = dpp_xor1_add(gs[g]);             // full 8-asset group sum

        // row sum from full group sums (lane-local)
        const float S = ((gs[0] + gs[1]) + (gs[2] + gs[3]))
                      + ((gs[4] + gs[5]) + (gs[6] + gs[7]));
        const float shift = (S - 1.0f) * (1.0f / NA);

        // all 8 group projections (redundant in both lanes of the pair)
        float u[NG];
#pragma unroll
        for (int g = 0; g < NG; ++g) {
            const float Aw  = fmaf(-8.0f, shift, gs[g]);   // dot after box shift
            const float e1  = fmaxf(Aw - gub_s[g], 0.0f);
            const float Aw2 = Aw - e1;                     // analytic recompute
            const float e2  = fminf(Aw2 - glb_s[g], 0.0f);
            u[g] = fmaf(e1 + e2, inv8, shift);
        }
        // fused update
#pragma unroll
        for (int i = 0; i < 32; ++i)
            w[i] -= u[i & 7];
    }

    // final box_simplex
#pragma unroll
    for (int i = 0; i < 32; ++i)
        w[i] = __builtin_amdgcn_fmed3f(w[i], lb0, ub0);
    float ps[NG];
#pragma unroll
    for (int g = 0; g < NG; ++g)
        ps[g] = (w[g] + w[g + 8]) + (w[g + 16] + w[g + 24]);
    const float ls = ((ps[0] + ps[1]) + (ps[2] + ps[3]))
                   + ((ps[4] + ps[5]) + (ps[6] + ps[7]));
    const float S = dpp_xor1_add(ls);                // pair total
    const float shift = (S - 1.0f) * (1.0f / NA);

#pragma unroll
    for (int m = 0; m < 4; ++m)
#pragma unroll
        for (int q = 0; q < 2; ++q) {
            float4 v;
            v.x = w[8 * m + 4 * q + 0] - shift;
            v.y = w[8 * m + 4 * q + 1] - shift;
            v.z = w[8 * m + 4 * q + 2] - shift;
            v.w = w[8 * m + 4 * q + 3] - shift;
            reinterpret_cast<float4*>(outr)[4 * m + 2 * h + q] = v;
        }
}

__global__ __launch_bounds__(256) void proj_generic(
    const float* __restrict__ x,
    const float* __restrict__ box_lb,
    const float* __restrict__ box_ub,
    const float* __restrict__ group_A,
    const float* __restrict__ group_lb,
    const float* __restrict__ group_ub,
    const int*  __restrict__ num_iter,
    float* __restrict__ out,
    int nrows)
{
    if (structural_ok(box_lb, box_ub, group_A, threadIdx.x & 63)) return;

    const int r = blockIdx.x * blockDim.x + threadIdx.x;
    if (r >= nrows) return;

    const float* __restrict__ xr = x + (size_t)r * NA;
    float* __restrict__ outr = out + (size_t)r * NA;

    float w[NA];
#pragma unroll
    for (int j = 0; j < NA; ++j) w[j] = xr[j];

    const int iters = *num_iter;

    for (int it = 0; it < iters; ++it) {
        float S = 0.0f;
#pragma unroll
        for (int j = 0; j < NA; ++j) {
            w[j] = fminf(fmaxf(w[j], box_lb[j]), box_ub[j]);
            S += w[j];
        }
        const float shift = (S - 1.0f) * (1.0f / NA);
#pragma unroll
        for (int j = 0; j < NA; ++j) w[j] -= shift;

        for (int g = 0; g < NG; ++g) {              // sequential groups
            const float* __restrict__ a = group_A + g * NA;
            float ns = 0.0f, Aw = 0.0f;
#pragma unroll
            for (int j = 0; j < NA; ++j) {
                const float av = a[j];
                ns = fmaf(av, av, ns);
                Aw = fmaf(av, w[j], Aw);
            }
            const float invg = 1.0f / (ns + 1e-9f);
            const float gub = group_ub[g], glb = group_lb[g];
            const float d1 = (Aw > gub) ? (Aw - gub) * invg : 0.0f;
#pragma unroll
            for (int j = 0; j < NA; ++j) w[j] = fmaf(-d1, a[j], w[j]);
            float Aw2 = 0.0f;
#pragma unroll
            for (int j = 0; j < NA; ++j) Aw2 = fmaf(a[j], w[j], Aw2);
            const float d2 = (Aw2 < glb) ? (Aw2 - glb) * invg : 0.0f;
#pragma unroll
            for (int j = 0; j < NA; ++j) w[j] = fmaf(-d2, a[j], w[j]);
        }
    }
    float S = 0.0f;
#pragma unroll
    for (int j = 0; j < NA; ++j) {
        w[j] = fminf(fmaxf(w[j], box_lb[j]), box_ub[j]);
        S += w[j];
    }
    const float shift = (S - 1.0f) * (1.0f / NA);
#pragma unroll
    for (int j = 0; j < NA; ++j) outr[j] = w[j] - shift;
}

extern "C" void kernel_launch(void* const* d_in, const int* in_sizes, int n_in,
                              void* d_out, int out_size, void* d_ws, size_t ws_size,
                              hipStream_t stream) {
    const float* x        = (const float*)d_in[0];
    const float* box_lb   = (const float*)d_in[1];
    const float* box_ub   = (const float*)d_in[2];
    const float* group_A  = (const float*)d_in[3];
    const float* group_lb = (const float*)d_in[4];
    const float* group_ub = (const float*)d_in[5];
    const int*   num_iter = (const int*)d_in[6];
    float* out = (float*)d_out;

    const int nrows = in_sizes[0] / NA;              // 262144

    // fast kernel: 2 lanes per row
    {
        const int total = nrows * 2;
        const int block = 256;
        const int grid = (total + block - 1) / block;
        proj_fast<<<grid, block, 0, stream>>>(x, box_lb, box_ub, group_A,
                                              group_lb, group_ub, num_iter,
                                              out, nrows);
    }
    // generic fallback: 1 row per thread (early-exits on this data)
    {
        const int block = 256;
        const int grid = (nrows + block - 1) / block;
        proj_generic<<<grid, block, 0, stream>>>(x, box_lb, box_ub, group_A,
                                                 group_lb, group_ub, num_iter,
                                                 out, nrows);
    }
}

// Round 6
// 135.262 us; speedup vs baseline: 1.1397x; 1.1397x over previous
//
#include <hip/hip_runtime.h>

// DifferentiableProjectionLayer: 262144 independent rows of 64 assets,
// 20 iters of {box clip + simplex shift + 8 disjoint group projections}.
//
// Chassis: R2's 8-lanes-per-row mapping (lane c owns the 8 assets of group
// c), which the register allocator handles cleanly (VGPR~36, no AGPR
// shuffling, no scratch). Row sum = 3-step butterfly (2x DPP quad_perm +
// 1 ds_swizzle xor4).
//
// Key addition: WAVE-UNIFORM EARLY EXIT. The loop is a non-expansive
// fixed-point map (alternating projections). Once an iteration's updates
// |shift| and |d_g| are all < 1e-6, every remaining iteration changes w by
// < ~2e-6, so skipping the rest perturbs the result by < 4e-5 (threshold
// is 9.2e-4). On this data ~99% of rows start feasible => most waves exit
// after iteration 1; ~6% of waves (containing a group-lb-violating row)
// run a few more until converged.
//
// proj_fast handles the structural case (one-hot A, uniform box bounds,
// verified wave-uniformly on device); proj_generic is the faithful general
// Dykstra fallback and early-exits when the fast kernel handled the data.

#define NA 64
#define NG 8
#define TOL 1e-6f

__device__ __forceinline__ float row8_allreduce_sum(float v) {
    // butterfly over the 8-lane row group: xor1, xor2 (DPP quad_perm), xor4 (swizzle)
    int j = __builtin_amdgcn_update_dpp(0, __builtin_bit_cast(int, v),
                                        0xB1 /*[1,0,3,2]*/, 0xF, 0xF, true);
    v += __builtin_bit_cast(float, j);
    j = __builtin_amdgcn_update_dpp(0, __builtin_bit_cast(int, v),
                                    0x4E /*[2,3,0,1]*/, 0xF, 0xF, true);
    v += __builtin_bit_cast(float, j);
    j = __builtin_amdgcn_ds_swizzle(__builtin_bit_cast(int, v), 0x101F /*xor 4*/);
    v += __builtin_bit_cast(float, j);
    return v;
}

__device__ __forceinline__ bool structural_ok(const float* __restrict__ box_lb,
                                              const float* __restrict__ box_ub,
                                              const float* __restrict__ group_A,
                                              int l) {
    const float lb0 = box_lb[0], ub0 = box_ub[0];
    bool ok = (box_lb[l] == lb0) && (box_ub[l] == ub0) && (lb0 <= ub0);
#pragma unroll
    for (int g = 0; g < NG; ++g) {
        const float expect = ((l & 7) == g) ? 1.0f : 0.0f;
        ok = ok && (group_A[g * NA + l] == expect);
    }
    return __all(ok);
}

__global__ __launch_bounds__(256) void proj_fast(
    const float* __restrict__ x,
    const float* __restrict__ box_lb,
    const float* __restrict__ box_ub,
    const float* __restrict__ group_A,
    const float* __restrict__ group_lb,
    const float* __restrict__ group_ub,
    const int*  __restrict__ num_iter,
    float* __restrict__ out,
    int nrows)
{
    if (!structural_ok(box_lb, box_ub, group_A, threadIdx.x & 63)) return;

    const int t = blockIdx.x * blockDim.x + threadIdx.x;
    const int r = t >> 3;     // row
    const int c = t & 7;      // group owned by this lane
    if (r >= nrows) return;

    const float* __restrict__ xr = x + (size_t)r * NA;
    float* __restrict__ outr = out + (size_t)r * NA;

    float w[8];
#pragma unroll
    for (int k = 0; k < 8; ++k) w[k] = xr[k * 8 + c];

    const float lb0 = box_lb[0], ub0 = box_ub[0];   // uniform -> SGPR
    const float glb = group_lb[c];
    const float gub = group_ub[c];

    const int iters = *num_iter;

    // ns = 8 (+1e-9 vanishes in f32) => inv = 0.125f exact; sumA = 8.
    const float inv8 = 1.0f / (8.0f + 1e-9f);       // == 0.125f

    for (int it = 0; it < iters; ++it) {
        // box clip + lane-local (group) sum
#pragma unroll
        for (int k = 0; k < 8; ++k)
            w[k] = __builtin_amdgcn_fmed3f(w[k], lb0, ub0);
        const float s01 = w[0] + w[1], s23 = w[2] + w[3];
        const float s45 = w[4] + w[5], s67 = w[6] + w[7];
        const float dota = (s01 + s23) + (s45 + s67);   // group c sum

        // row sum across the 8 lanes
        const float S = row8_allreduce_sum(dota);
        const float shift = fmaf(S, 1.0f / NA, -1.0f / NA);

        // group projection (upper, analytic recompute, lower)
        const float Aw  = fmaf(-8.0f, shift, dota);
        const float e1  = fmaxf(Aw - gub, 0.0f);
        const float Aw2 = Aw - e1;                      // e1*(8*inv8) == e1
        const float e2  = fminf(Aw2 - glb, 0.0f);
        const float d   = (e1 + e2) * inv8;
        const float u   = shift + d;

#pragma unroll
        for (int k = 0; k < 8; ++k) w[k] -= u;

        // wave-uniform convergence exit: remaining iterations would change
        // w by < ~(iters-it)*2*TOL, far below the accuracy threshold.
        if (__all(__builtin_fabsf(shift) < TOL && __builtin_fabsf(d) < TOL))
            break;
    }

    // final box_simplex
#pragma unroll
    for (int k = 0; k < 8; ++k)
        w[k] = __builtin_amdgcn_fmed3f(w[k], lb0, ub0);
    const float s01 = w[0] + w[1], s23 = w[2] + w[3];
    const float s45 = w[4] + w[5], s67 = w[6] + w[7];
    const float S = row8_allreduce_sum((s01 + s23) + (s45 + s67));
    const float shift = fmaf(S, 1.0f / NA, -1.0f / NA);

#pragma unroll
    for (int k = 0; k < 8; ++k)
        outr[k * 8 + c] = w[k] - shift;
}

__global__ __launch_bounds__(256) void proj_generic(
    const float* __restrict__ x,
    const float* __restrict__ box_lb,
    const float* __restrict__ box_ub,
    const float* __restrict__ group_A,
    const float* __restrict__ group_lb,
    const float* __restrict__ group_ub,
    const int*  __restrict__ num_iter,
    float* __restrict__ out,
    int nrows)
{
    if (structural_ok(box_lb, box_ub, group_A, threadIdx.x & 63)) return;

    const int r = blockIdx.x * blockDim.x + threadIdx.x;
    if (r >= nrows) return;

    const float* __restrict__ xr = x + (size_t)r * NA;
    float* __restrict__ outr = out + (size_t)r * NA;

    float w[NA];
#pragma unroll
    for (int j = 0; j < NA; ++j) w[j] = xr[j];

    const int iters = *num_iter;

    for (int it = 0; it < iters; ++it) {
        float S = 0.0f;
#pragma unroll
        for (int j = 0; j < NA; ++j) {
            w[j] = fminf(fmaxf(w[j], box_lb[j]), box_ub[j]);
            S += w[j];
        }
        const float shift = (S - 1.0f) * (1.0f / NA);
#pragma unroll
        for (int j = 0; j < NA; ++j) w[j] -= shift;

        for (int g = 0; g < NG; ++g) {              // sequential groups
            const float* __restrict__ a = group_A + g * NA;
            float ns = 0.0f, Aw = 0.0f;
#pragma unroll
            for (int j = 0; j < NA; ++j) {
                const float av = a[j];
                ns = fmaf(av, av, ns);
                Aw = fmaf(av, w[j], Aw);
            }
            const float invg = 1.0f / (ns + 1e-9f);
            const float gub = group_ub[g], glb = group_lb[g];
            const float d1 = (Aw > gub) ? (Aw - gub) * invg : 0.0f;
#pragma unroll
            for (int j = 0; j < NA; ++j) w[j] = fmaf(-d1, a[j], w[j]);
            float Aw2 = 0.0f;
#pragma unroll
            for (int j = 0; j < NA; ++j) Aw2 = fmaf(a[j], w[j], Aw2);
            const float d2 = (Aw2 < glb) ? (Aw2 - glb) * invg : 0.0f;
#pragma unroll
            for (int j = 0; j < NA; ++j) w[j] = fmaf(-d2, a[j], w[j]);
        }
    }
    float S = 0.0f;
#pragma unroll
    for (int j = 0; j < NA; ++j) {
        w[j] = fminf(fmaxf(w[j], box_lb[j]), box_ub[j]);
        S += w[j];
    }
    const float shift = (S - 1.0f) * (1.0f / NA);
#pragma unroll
    for (int j = 0; j < NA; ++j) outr[j] = w[j] - shift;
}

extern "C" void kernel_launch(void* const* d_in, const int* in_sizes, int n_in,
                              void* d_out, int out_size, void* d_ws, size_t ws_size,
                              hipStream_t stream) {
    const float* x        = (const float*)d_in[0];
    const float* box_lb   = (const float*)d_in[1];
    const float* box_ub   = (const float*)d_in[2];
    const float* group_A  = (const float*)d_in[3];
    const float* group_lb = (const float*)d_in[4];
    const float* group_ub = (const float*)d_in[5];
    const int*   num_iter = (const int*)d_in[6];
    float* out = (float*)d_out;

    const int nrows = in_sizes[0] / NA;              // 262144

    // fast kernel: 8 lanes per row
    {
        const int total = nrows * 8;
        const int block = 256;
        const int grid = (total + block - 1) / block;
        proj_fast<<<grid, block, 0, stream>>>(x, box_lb, box_ub, group_A,
                                              group_lb, group_ub, num_iter,
                                              out, nrows);
    }
    // generic fallback: 1 row per thread (early-exits on this data)
    {
        const int block = 256;
        const int grid = (nrows + block - 1) / block;
        proj_generic<<<grid, block, 0, stream>>>(x, box_lb, box_ub, group_A,
                                                 group_lb, group_ub, num_iter,
                                                 out, nrows);
    }
}

// Round 8
// 127.910 us; speedup vs baseline: 1.2052x; 1.0575x over previous
//
#include <hip/hip_runtime.h>

// DifferentiableProjectionLayer: 262144 independent rows of 64 assets,
// 20 iters of {box clip + simplex shift + 8 disjoint group projections}.
//
// Single merged kernel, 8 lanes per row (lane c owns the 8 assets of group
// c). Both the structural fast path and the faithful generic fallback use
// the same w[8] register shape (~48 VGPR worst case), so the R3 regalloc
// pollution cannot recur. Wave-uniform branch; on this data the fast path
// always runs and exits after ~1 iteration (non-expansive fixed-point map:
// once |shift|,|d| < 1e-6 the remaining iterations move w < 4e-5, far
// below the 9.2e-4 accuracy threshold).
//
// Global I/O is vectorized via an in-wave LDS transpose: each wave loads
// its 8 rows (2 KB) as 2 float4/lane, transposes through a 72-float-stride
// LDS slice (<=2-way bank aliasing = free), and reverses for the store.
// 16 scalar VMEM ops/thread -> 4 vector ops/thread.

#define NA 64
#define NG 8
#define TOL 1e-6f
#define RS 72                 // LDS row stride in floats (pad breaks 64)
#define ROWS_PER_BLOCK 32
#define ROWS_PER_WAVE 8

__device__ __forceinline__ float row8_allreduce_sum(float v) {
    // butterfly over the 8-lane row group: xor1, xor2 (DPP quad_perm), xor4 (swizzle)
    int j = __builtin_amdgcn_update_dpp(0, __builtin_bit_cast(int, v),
                                        0xB1 /*[1,0,3,2]*/, 0xF, 0xF, true);
    v += __builtin_bit_cast(float, j);
    j = __builtin_amdgcn_update_dpp(0, __builtin_bit_cast(int, v),
                                    0x4E /*[2,3,0,1]*/, 0xF, 0xF, true);
    v += __builtin_bit_cast(float, j);
    j = __builtin_amdgcn_ds_swizzle(__builtin_bit_cast(int, v), 0x101F /*xor 4*/);
    v += __builtin_bit_cast(float, j);
    return v;
}

__global__ __launch_bounds__(256) void proj_kernel(
    const float* __restrict__ x,
    const float* __restrict__ box_lb,
    const float* __restrict__ box_ub,
    const float* __restrict__ group_A,
    const float* __restrict__ group_lb,
    const float* __restrict__ group_ub,
    const int*  __restrict__ num_iter,
    float* __restrict__ out,
    int nrows)
{
    __shared__ float lds[ROWS_PER_BLOCK * RS];   // 9216 B

    const int tid  = threadIdx.x;
    const int wave = tid >> 6;
    const int lane = tid & 63;
    const int lr   = lane >> 3;                  // row within wave
    const int c    = lane & 7;                   // group owned by this lane

    const size_t wrow0 = (size_t)blockIdx.x * ROWS_PER_BLOCK + (size_t)wave * ROWS_PER_WAVE;
    const size_t r = wrow0 + (size_t)lr;         // this thread's row
    const bool fullwave = (wrow0 + ROWS_PER_WAVE) <= (size_t)nrows;
    const bool valid = r < (size_t)nrows;

    float* lw = lds + wave * ROWS_PER_WAVE * RS; // per-wave private slice

    // ---- issue x loads immediately (both paths need w) ----
    float4 v0, v1;
    if (fullwave) {
        const float4* src = reinterpret_cast<const float4*>(x + wrow0 * NA);
        v0 = src[lane];                          // quad idx lane: row lane>>4
        v1 = src[lane + 64];                     // row 4+(lane>>4)
    }

    // ---- structural check (overlaps the loads) ----
    const float lb0 = box_lb[0], ub0 = box_ub[0];
    bool ok = (box_lb[lane] == lb0) && (box_ub[lane] == ub0) && (lb0 <= ub0);
#pragma unroll
    for (int g = 0; g < NG; ++g) {
        const float expect = ((lane & 7) == g) ? 1.0f : 0.0f;
        ok = ok && (group_A[g * NA + lane] == expect);
    }
    const bool fast = __all(ok);                 // identical for every wave

    // ---- LDS transpose: global-coalesced -> lane-owns-group layout ----
    if (fullwave) {
        *reinterpret_cast<float4*>(lw + (lane >> 4) * RS + (lane & 15) * 4) = v0;
        *reinterpret_cast<float4*>(lw + ((lane >> 4) + 4) * RS + (lane & 15) * 4) = v1;
    }
    __syncthreads();
    float w[8];
    if (fullwave) {
#pragma unroll
        for (int k = 0; k < 8; ++k) w[k] = lw[lr * RS + k * 8 + c];
    } else if (valid) {
#pragma unroll
        for (int k = 0; k < 8; ++k) w[k] = x[r * NA + k * 8 + c];
    }

    const int iters = *num_iter;
    float shift = 0.0f;

    if (fast) {
        // ============== FAST PATH (structural data) ==============
        const float glb = group_lb[c];
        const float gub = group_ub[c];
        // ns = 8 (+1e-9 vanishes in f32) => inv = 0.125f exact.
        const float inv8 = 1.0f / (8.0f + 1e-9f);

        for (int it = 0; it < iters; ++it) {
#pragma unroll
            for (int k = 0; k < 8; ++k)
                w[k] = __builtin_amdgcn_fmed3f(w[k], lb0, ub0);
            const float s01 = w[0] + w[1], s23 = w[2] + w[3];
            const float s45 = w[4] + w[5], s67 = w[6] + w[7];
            const float dota = (s01 + s23) + (s45 + s67);     // group c sum

            const float S = row8_allreduce_sum(dota);
            const float sh = fmaf(S, 1.0f / NA, -1.0f / NA);

            const float Aw  = fmaf(-8.0f, sh, dota);
            const float e1  = fmaxf(Aw - gub, 0.0f);
            const float Aw2 = Aw - e1;                        // e1*(8*inv8)==e1
            const float e2  = fminf(Aw2 - glb, 0.0f);
            const float d   = (e1 + e2) * inv8;
            const float u   = sh + d;
#pragma unroll
            for (int k = 0; k < 8; ++k) w[k] -= u;

            if (__all(__builtin_fabsf(sh) < TOL && __builtin_fabsf(d) < TOL))
                break;
        }
        // final box_simplex (clip + shift; shift applied at store)
#pragma unroll
        for (int k = 0; k < 8; ++k)
            w[k] = __builtin_amdgcn_fmed3f(w[k], lb0, ub0);
        const float s01 = w[0] + w[1], s23 = w[2] + w[3];
        const float s45 = w[4] + w[5], s67 = w[6] + w[7];
        const float S = row8_allreduce_sum((s01 + s23) + (s45 + s67));
        shift = fmaf(S, 1.0f / NA, -1.0f / NA);
    } else {
        // ============== GENERIC PATH (faithful Dykstra) ==============
        float lbv[8], ubv[8];
#pragma unroll
        for (int k = 0; k < 8; ++k) {
            lbv[k] = box_lb[k * 8 + c];
            ubv[k] = box_ub[k * 8 + c];
        }
        for (int it = 0; it < iters; ++it) {
            float S = 0.0f;
#pragma unroll
            for (int k = 0; k < 8; ++k) {
                w[k] = fminf(fmaxf(w[k], lbv[k]), ubv[k]);
                S += w[k];
            }
            S = row8_allreduce_sum(S);
            const float sh = (S - 1.0f) * (1.0f / NA);
#pragma unroll
            for (int k = 0; k < 8; ++k) w[k] -= sh;

            for (int g = 0; g < NG; ++g) {        // sequential groups
                float a[8];
#pragma unroll
                for (int k = 0; k < 8; ++k) a[k] = group_A[g * NA + k * 8 + c];
                float ns = 0.0f, Aw = 0.0f;
#pragma unroll
                for (int k = 0; k < 8; ++k) {
                    ns = fmaf(a[k], a[k], ns);
                    Aw = fmaf(a[k], w[k], Aw);
                }
                ns = row8_allreduce_sum(ns);
                Aw = row8_allreduce_sum(Aw);
                const float invg = 1.0f / (ns + 1e-9f);
                const float gub = group_ub[g], glb = group_lb[g];
                const float d1 = (Aw > gub) ? (Aw - gub) * invg : 0.0f;
#pragma unroll
                for (int k = 0; k < 8; ++k) w[k] = fmaf(-d1, a[k], w[k]);
                float Aw2 = 0.0f;
#pragma unroll
                for (int k = 0; k < 8; ++k) Aw2 = fmaf(a[k], w[k], Aw2);
                Aw2 = row8_allreduce_sum(Aw2);
                const float d2 = (Aw2 < glb) ? (Aw2 - glb) * invg : 0.0f;
#pragma unroll
                for (int k = 0; k < 8; ++k) w[k] = fmaf(-d2, a[k], w[k]);
            }
        }
        float S = 0.0f;
#pragma unroll
        for (int k = 0; k < 8; ++k) {
            w[k] = fminf(fmaxf(w[k], lbv[k]), ubv[k]);
            S += w[k];
        }
        S = row8_allreduce_sum(S);
        shift = (S - 1.0f) * (1.0f / NA);
    }

    // ---- store: reverse LDS transpose -> coalesced float4 ----
    if (fullwave) {
#pragma unroll
        for (int k = 0; k < 8; ++k)
            lw[lr * RS + k * 8 + c] = w[k] - shift;
    }
    __syncthreads();
    if (fullwave) {
        const float4 q0 = *reinterpret_cast<const float4*>(lw + (lane >> 4) * RS + (lane & 15) * 4);
        const float4 q1 = *reinterpret_cast<const float4*>(lw + ((lane >> 4) + 4) * RS + (lane & 15) * 4);
        float4* dst = reinterpret_cast<float4*>(out + wrow0 * NA);
        dst[lane] = q0;
        dst[lane + 64] = q1;
    } else if (valid) {
#pragma unroll
        for (int k = 0; k < 8; ++k)
            out[r * NA + k * 8 + c] = w[k] - shift;
    }
}

extern "C" void kernel_launch(void* const* d_in, const int* in_sizes, int n_in,
                              void* d_out, int out_size, void* d_ws, size_t ws_size,
                              hipStream_t stream) {
    const float* x        = (const float*)d_in[0];
    const float* box_lb   = (const float*)d_in[1];
    const float* box_ub   = (const float*)d_in[2];
    const float* group_A  = (const float*)d_in[3];
    const float* group_lb = (const float*)d_in[4];
    const float* group_ub = (const float*)d_in[5];
    const int*   num_iter = (const int*)d_in[6];
    float* out = (float*)d_out;

    const int nrows = in_sizes[0] / NA;          // 262144
    const int total = nrows * 8;                 // 8 lanes per row
    const int block = 256;
    const int grid = (total + block - 1) / block;

    proj_kernel<<<grid, block, 0, stream>>>(x, box_lb, box_ub, group_A,
                                            group_lb, group_ub, num_iter,
                                            out, nrows);
}